// Round 13
// baseline (391.528 us; speedup 1.0000x reference)
//
#include <hip/hip_runtime.h>
#include <math.h>

#define S 4
#define G 3
#define NN 20000
#define NP (NN+1)        // feature slices padded with a zero row at index NN
#define EE 320000
#define D 64
#define SG (S*G)

#define RGS 32           // dst-ranges per graph
#define RNODES2 625      // NN / RGS
#define BCAP 12000       // bucket capacity per (sg,range); mean 10000
#define CHUNKA 100       // edge chunks per sg in binA; 320000/100 = 3200 edges/block

// layer task swizzle: 12 sg x 314 tiles = 3768 = 8 XCD x 471 tasks
#define LTILES 314
#define LTASKS (12*LTILES)
#define LPERX  (LTASKS/8)   // 471

static __device__ __forceinline__ float rcpf(float x){ return __builtin_amdgcn_rcpf(x); }
static __device__ __forceinline__ float sigmf(float x){ return rcpf(1.0f + __expf(-x)); }
// fast tanh: 1 - 2/(e^{2x}+1), v_rcp for the divide; saturates correctly
static __device__ __forceinline__ float tanhf_fast(float x){
    float t = __expf(2.0f*x);
    return 1.0f - 2.0f*rcpf(t + 1.0f);
}

// float -> bf16 bits, round-nearest-even
static __device__ __forceinline__ unsigned short f2bf(float f){
    union { float f; unsigned u; } v; v.f = f;
    unsigned r = v.u + 0x7FFF + ((v.u >> 16) & 1);
    return (unsigned short)(r >> 16);
}

typedef short bf16x8 __attribute__((ext_vector_type(8)));
typedef float f32x4  __attribute__((ext_vector_type(4)));

// ---------------- Phase A: bin edges into 32 dst-range buckets, packed (dstLoc<<15)|src ----------------

__global__ __launch_bounds__(256) void binA_kernel(const int* __restrict__ ei,
                                                   int* __restrict__ bcur,
                                                   int* __restrict__ bkt){
    __shared__ int wcnt[4*RGS];
    __shared__ int wb[4*RGS];
    int chunk = blockIdx.x, sg = blockIdx.y;
    int tid = threadIdx.x, w = tid >> 6;
    const int* srcp = ei + (size_t)(sg*2 + 0)*EE;
    const int* dstp = ei + (size_t)(sg*2 + 1)*EE;
    const int EPC = EE/CHUNKA;               // 3200
    int start = chunk*EPC, end = start + EPC;

    for (int it = 0; it < (EPC + 1023)/1024; ++it){
        if (tid < 4*RGS) wcnt[tid] = 0;
        __syncthreads();
        int e = start + it*1024 + tid*4;
        bool valid = e < end;
        int d_[4], s_[4], r_[4], dl_[4], rk_[4];
        if (valid){
            int4 d4 = *(const int4*)&dstp[e];
            int4 s4 = *(const int4*)&srcp[e];
            d_[0]=d4.x; d_[1]=d4.y; d_[2]=d4.z; d_[3]=d4.w;
            s_[0]=s4.x; s_[1]=s4.y; s_[2]=s4.z; s_[3]=s4.w;
            #pragma unroll
            for (int j = 0; j < 4; ++j){
                int r = d_[j] / RNODES2;
                r_[j]  = r;
                dl_[j] = d_[j] - r*RNODES2;
                rk_[j] = atomicAdd(&wcnt[w*RGS + r], 1);
            }
        }
        __syncthreads();
        if (tid < RGS){
            int c0 = wcnt[0*RGS+tid], c1 = wcnt[1*RGS+tid];
            int c2 = wcnt[2*RGS+tid], c3 = wcnt[3*RGS+tid];
            int tot = c0+c1+c2+c3;
            int gb = 0;
            if (tot > 0) gb = atomicAdd(&bcur[sg*RGS + tid], tot);
            wb[0*RGS+tid] = gb;
            wb[1*RGS+tid] = gb + c0;
            wb[2*RGS+tid] = gb + c0 + c1;
            wb[3*RGS+tid] = gb + c0 + c1 + c2;
        }
        __syncthreads();
        if (valid){
            #pragma unroll
            for (int j = 0; j < 4; ++j){
                int pos = wb[w*RGS + r_[j]] + rk_[j];
                if (pos < BCAP)
                    bkt[(size_t)(sg*RGS + r_[j])*BCAP + pos] = (dl_[j] << 15) | s_[j];
            }
        }
    }
}

// ---------------- Phase B: per (sg,range): hist -> scan -> CSR segment -> in-place dump ----------------
// Final CSR entries are PRE-SCALED byte offsets: src*128 (row stride of bf16 feature slice).

__global__ __launch_bounds__(256) void buildB_kernel(int* __restrict__ bkt,
                                                     const int* __restrict__ bcur,
                                                     int* __restrict__ off2,
                                                     int* __restrict__ deg2){
    __shared__ int hist[RNODES2];
    __shared__ int pref[RNODES2];
    __shared__ int seg[BCAP];
    __shared__ int sums[256];
    int sg = blockIdx.x / RGS, rg = blockIdx.x % RGS;
    int tid = threadIdx.x;
    int cnt = bcur[sg*RGS + rg];
    if (cnt > BCAP) cnt = BCAP;
    size_t base = (size_t)(sg*RGS + rg)*BCAP;

    for (int i = tid; i < RNODES2; i += 256) hist[i] = 0;
    __syncthreads();
    for (int j = tid; j < cnt; j += 256)
        atomicAdd(&hist[bkt[base + j] >> 15], 1);
    __syncthreads();

    int lo = tid*3, hi = min(lo+3, RNODES2);
    int s = 0;
    for (int i = lo; i < hi; ++i) s += hist[i];
    sums[tid] = s; __syncthreads();
    for (int ofs = 1; ofs < 256; ofs <<= 1){
        int v = (tid >= ofs) ? sums[tid-ofs] : 0;
        __syncthreads();
        sums[tid] += v;
        __syncthreads();
    }
    int run = sums[tid] - s;
    int gnode = sg*NN + rg*RNODES2;
    for (int i = lo; i < hi; ++i){
        pref[i] = run;
        off2[gnode + i] = (int)base + run;
        deg2[gnode + i] = hist[i];
        run += hist[i];
    }
    __syncthreads();

    for (int j = tid; j < cnt; j += 256){
        int p = bkt[base + j];
        int slot = atomicAdd(&pref[p >> 15], 1);
        seg[slot] = p & 0x7FFF;
    }
    __syncthreads();

    for (int j = tid; j < cnt; j += 256) bkt[base + j] = seg[j] << 7;  // src*128 bytes
}

// ---------------- x -> bf16 convert (padded NP-row slices) + zero the sentinel rows ----------------

__global__ __launch_bounds__(256) void convert_kernel(const float* __restrict__ x,
                                                      unsigned short* __restrict__ xb,
                                                      unsigned short* __restrict__ h1b,
                                                      unsigned short* __restrict__ h2b){
    int idx = blockIdx.x*256 + threadIdx.x;
    const int mainN = SG*NN*16;
    if (idx < mainN){
        int sg = idx / (NN*16), rem = idx - sg*(NN*16);
        float4 v = ((const float4*)x)[idx];
        uint2 pk;
        pk.x = (unsigned)f2bf(v.x) | ((unsigned)f2bf(v.y) << 16);
        pk.y = (unsigned)f2bf(v.z) | ((unsigned)f2bf(v.w) << 16);
        ((uint2*)xb)[(size_t)sg*(NP*16) + rem] = pk;
    } else {
        int t = idx - mainN;          // zero rows: 3 arrays x SG x 16 chunks
        if (t < SG*3*16){
            int which = t / (SG*16), r = t - which*(SG*16);
            int sg = r >> 4, c = r & 15;
            unsigned short* dst = (which == 0) ? xb : ((which == 1) ? h1b : h2b);
            ((uint2*)dst)[((size_t)sg*NP + NN)*16 + c] = (uint2){0,0};
        }
    }
}

// ---------------- weight prep: all bf16, [col][k] layouts ----------------

__global__ __launch_bounds__(256) void wprep2_kernel(const float* __restrict__ W1l,
                                                     const float* __restrict__ W1r,
                                                     const float* __restrict__ W2l,
                                                     const float* __restrict__ W2r,
                                                     const float* __restrict__ Wih,
                                                     const float* __restrict__ Whh,
                                                     const float* __restrict__ bih,
                                                     const float* __restrict__ bhh,
                                                     unsigned short* __restrict__ WL1,
                                                     unsigned short* __restrict__ WL2,
                                                     unsigned short* __restrict__ Wt,
                                                     float* __restrict__ bc){
    int idx = blockIdx.x*256 + threadIdx.x;
    if (idx < 24576){
        int g = idx >> 13, rem = idx & 8191, col = rem >> 7, k = rem & 127;
        float v = (k < 64) ? W1l[((size_t)g*64 + k)*64 + col]
                           : W1r[((size_t)g*64 + (k-64))*64 + col];
        WL1[idx] = f2bf(v);
    } else if (idx < 49152){
        int t = idx - 24576;
        int g = t >> 13, rem = t & 8191, col = rem >> 7, k = rem & 127;
        float v = (k < 64) ? W2l[((size_t)g*64 + k)*64 + col]
                           : W2r[((size_t)g*64 + (k-64))*64 + col];
        WL2[t] = f2bf(v);
    } else if (idx < 81920){
        int t = idx - 49152;
        int col = t >> 7, k = t & 127;
        float v = (k < 64) ? Wih[col*64 + k] : Whh[col*64 + (k - 64)];
        Wt[t] = f2bf(v);
    } else if (idx < 82176){
        int t = idx - 81920;
        bc[t] = bih[t] + bhh[t];
    }
}

// ---------------- SAGE layer: barrier-free, per-wave slices; dual-row gather,
// unconditional sentinel-clamped loads (16 in flight); XCD-affinity swizzle ----------------

#define WP 72

__global__ __launch_bounds__(256) void layer_kernel(const unsigned short* __restrict__ xb,
                                                    const int* __restrict__ off2,
                                                    const int* __restrict__ deg2,
                                                    const int* __restrict__ csr,
                                                    const unsigned short* __restrict__ WL,
                                                    const float* __restrict__ bias,
                                                    unsigned short* __restrict__ outb){
    __shared__ unsigned short sM[4][16*WP];  // mean slices
    __shared__ unsigned short sO[4][16*WP];  // out slices
    // XCD-affinity swizzle: dispatch round-robins blocks over 8 XCDs (L%8).
    int L = blockIdx.x;
    int xcd = L & 7, k = L >> 3;
    int task = xcd*LPERX + k;
    int sg = task / LTILES;
    int tile = task - sg*LTILES;
    if (tile >= (NN + 63)/64) return;   // pad task (no barriers in kernel -> safe)
    int g = sg % G;
    int tid = threadIdx.x;
    int row0 = tile*64;
    const unsigned short* inb = xb + (size_t)sg*NP*D;
    const char* inbc = (const char*)inb;
    const int ZOFF = NN*128;            // byte offset of the zero row

    int wave = tid >> 6, lane = tid & 63;
    int i0 = row0 + wave*16;

    // aggregation: 8 groups x 8 lanes; group owns rows (gp, 8+gp) jointly
    {
        int gp = lane >> 3, fl = lane & 7;
        int ii = min(i0 + (lane & 15), NN-1);
        int val = (lane < 16) ? off2[sg*NN + ii] : ((lane < 32) ? deg2[sg*NN + ii] : 0);
        int r0loc = gp, r1loc = 8 + gp;
        int a0  = __shfl(val, r0loc, 64);
        int dg0 = __shfl(val, 16 + r0loc, 64);
        int a1  = __shfl(val, r1loc, 64);
        int dg1 = __shfl(val, 16 + r1loc, 64);
        if (i0 + r0loc >= NN) dg0 = 0;
        if (i0 + r1loc >= NN) dg1 = 0;
        float acc0[8] = {0,0,0,0,0,0,0,0};
        float acc1[8] = {0,0,0,0,0,0,0,0};
        int mx = max(dg0, dg1);
        for (int base = 0; base < mx; base += 8){
            // unconditional csr loads (within bkt allocation), clamp to zero-row sentinel
            int c0v = csr[a0 + base + fl];
            int c1v = csr[a1 + base + fl];
            int my0 = (base + fl < dg0) ? c0v : ZOFF;
            int my1 = (base + fl < dg1) ? c1v : ZOFF;
            // phase 1: issue all 16 gathers unconditionally (sentinel rows add 0)
            uint4 v0[8], v1[8];
            #pragma unroll
            for (int j = 0; j < 8; ++j){
                int o0 = __shfl(my0, gp*8 + j, 64);
                int o1 = __shfl(my1, gp*8 + j, 64);
                v0[j] = *(const uint4*)(inbc + o0 + fl*16);
                v1[j] = *(const uint4*)(inbc + o1 + fl*16);
            }
            // phase 2: unpack + accumulate
            #pragma unroll
            for (int j = 0; j < 8; ++j){
                acc0[0] += __uint_as_float(v0[j].x << 16);
                acc0[1] += __uint_as_float(v0[j].x & 0xFFFF0000u);
                acc0[2] += __uint_as_float(v0[j].y << 16);
                acc0[3] += __uint_as_float(v0[j].y & 0xFFFF0000u);
                acc0[4] += __uint_as_float(v0[j].z << 16);
                acc0[5] += __uint_as_float(v0[j].z & 0xFFFF0000u);
                acc0[6] += __uint_as_float(v0[j].w << 16);
                acc0[7] += __uint_as_float(v0[j].w & 0xFFFF0000u);
                acc1[0] += __uint_as_float(v1[j].x << 16);
                acc1[1] += __uint_as_float(v1[j].x & 0xFFFF0000u);
                acc1[2] += __uint_as_float(v1[j].y << 16);
                acc1[3] += __uint_as_float(v1[j].y & 0xFFFF0000u);
                acc1[4] += __uint_as_float(v1[j].z << 16);
                acc1[5] += __uint_as_float(v1[j].z & 0xFFFF0000u);
                acc1[6] += __uint_as_float(v1[j].w << 16);
                acc1[7] += __uint_as_float(v1[j].w & 0xFFFF0000u);
            }
        }
        float inv0 = (dg0 > 0) ? rcpf((float)dg0) : 0.0f;
        float inv1 = (dg1 > 0) ? rcpf((float)dg1) : 0.0f;
        uint4 pk;
        pk.x = (unsigned)f2bf(acc0[0]*inv0) | ((unsigned)f2bf(acc0[1]*inv0) << 16);
        pk.y = (unsigned)f2bf(acc0[2]*inv0) | ((unsigned)f2bf(acc0[3]*inv0) << 16);
        pk.z = (unsigned)f2bf(acc0[4]*inv0) | ((unsigned)f2bf(acc0[5]*inv0) << 16);
        pk.w = (unsigned)f2bf(acc0[6]*inv0) | ((unsigned)f2bf(acc0[7]*inv0) << 16);
        *(uint4*)&sM[wave][r0loc*WP + fl*8] = pk;
        pk.x = (unsigned)f2bf(acc1[0]*inv1) | ((unsigned)f2bf(acc1[1]*inv1) << 16);
        pk.y = (unsigned)f2bf(acc1[2]*inv1) | ((unsigned)f2bf(acc1[3]*inv1) << 16);
        pk.z = (unsigned)f2bf(acc1[4]*inv1) | ((unsigned)f2bf(acc1[5]*inv1) << 16);
        pk.w = (unsigned)f2bf(acc1[6]*inv1) | ((unsigned)f2bf(acc1[7]*inv1) << 16);
        *(uint4*)&sM[wave][r1loc*WP + fl*8] = pk;
    }
    // no barrier: consumers are this same wave (lgkmcnt ordering)

    int n0 = lane & 15, q = lane >> 4;
    const unsigned short* WLg = WL + (size_t)g*64*128;
    f32x4 accv[4];
    #pragma unroll
    for (int ct = 0; ct < 4; ++ct) accv[ct] = (f32x4){0.f,0.f,0.f,0.f};
    int irow = min(i0 + n0, NN-1);
    #pragma unroll
    for (int kc = 0; kc < 4; ++kc){
        bf16x8 af;
        if (kc < 2) af = *(const bf16x8*)&sM[wave][n0*WP + kc*32 + q*8];
        else        af = *(const bf16x8*)&inb[(size_t)irow*D + (kc-2)*32 + q*8];
        #pragma unroll
        for (int ct = 0; ct < 4; ++ct){
            bf16x8 bfr = *(const bf16x8*)&WLg[(ct*16 + n0)*128 + kc*32 + q*8];
            accv[ct] = __builtin_amdgcn_mfma_f32_16x16x32_bf16(af, bfr, accv[ct], 0, 0, 0);
        }
    }
    #pragma unroll
    for (int ct = 0; ct < 4; ++ct){
        float bv = bias[g*64 + ct*16 + n0];
        #pragma unroll
        for (int reg = 0; reg < 4; ++reg)
            sO[wave][(q*4+reg)*WP + ct*16 + n0] = f2bf(tanhf_fast(accv[ct][reg] + bv));
    }
    #pragma unroll
    for (int pass = 0; pass < 2; ++pass){
        int rloc = pass*8 + (lane >> 3), chunk = lane & 7;
        int i = i0 + rloc;
        if (i < NN){
            uint4 v = *(const uint4*)&sO[wave][rloc*WP + chunk*8];
            *(uint4*)&outb[((size_t)sg*NP + i)*D + chunk*8] = v;
        }
    }
}

// ---------------- LSTM: col-partitioned waves; Wt read once per block; 3 barriers ----------------

__global__ __launch_bounds__(256) void lstm_kernel(const unsigned short* __restrict__ h2b,
                                                   const unsigned short* __restrict__ Wt,
                                                   const float* __restrict__ bc,
                                                   float* __restrict__ out){
    __shared__ unsigned short sH[64*WP];  // 9.2 KB, whole block's h
    int tid = threadIdx.x;
    int b0 = blockIdx.x * 64;
    int wave = tid >> 6, lane = tid & 63;
    int n0 = lane & 15, q = lane >> 4;
    int jcol = wave*16 + n0;              // output col j in [0,64)

    float bb[4];
    #pragma unroll
    for (int T = 0; T < 4; ++T) bb[T] = bc[T*64 + jcol];

    float c[4][4];  // [rt][reg]
    #pragma unroll
    for (int rt = 0; rt < 4; ++rt)
        #pragma unroll
        for (int reg = 0; reg < 4; ++reg) c[rt][reg] = 0.0f;

    int s_[4], n_[4];
    #pragma unroll
    for (int rt = 0; rt < 4; ++rt){
        int b = b0 + rt*16 + n0;
        s_[rt] = b / NN; n_[rt] = b - s_[rt]*NN;
    }

    #pragma unroll
    for (int t = 0; t < G; ++t){
        f32x4 accv[4][4];  // [rt][T]
        #pragma unroll
        for (int rt = 0; rt < 4; ++rt)
            #pragma unroll
            for (int T = 0; T < 4; ++T) accv[rt][T] = (f32x4){0.f,0.f,0.f,0.f};

        int nkc = (t == 0) ? 2 : 4;
        #pragma unroll
        for (int kc = 0; kc < 4; ++kc){
            if (kc >= nkc) break;
            bf16x8 af[4];
            #pragma unroll
            for (int rt = 0; rt < 4; ++rt){
                if (kc < 2) af[rt] = *(const bf16x8*)&h2b[((size_t)(s_[rt]*G + t)*NP + n_[rt])*D + kc*32 + q*8];
                else        af[rt] = *(const bf16x8*)&sH[(rt*16 + n0)*WP + (kc-2)*32 + q*8];
            }
            #pragma unroll
            for (int T = 0; T < 4; ++T){
                int ct = T*4 + wave;
                bf16x8 bfr = *(const bf16x8*)&Wt[(ct*16 + n0)*128 + kc*32 + q*8];
                #pragma unroll
                for (int rt = 0; rt < 4; ++rt)
                    accv[rt][T] = __builtin_amdgcn_mfma_f32_16x16x32_bf16(af[rt], bfr, accv[rt][T], 0, 0, 0);
            }
        }
        if (t > 0) __syncthreads();   // WAR: all sH reads done before overwrite

        #pragma unroll
        for (int rt = 0; rt < 4; ++rt){
            #pragma unroll
            for (int reg = 0; reg < 4; ++reg){
                float ig = sigmf(accv[rt][0][reg] + bb[0]);
                float fg = sigmf(accv[rt][1][reg] + bb[1]);
                float gg = tanhf_fast(accv[rt][2][reg] + bb[2]);
                float og = sigmf(accv[rt][3][reg] + bb[3]);
                float cn = fg*c[rt][reg] + ig*gg;
                c[rt][reg] = cn;
                float hv = og * tanhf_fast(cn);
                int row = rt*16 + q*4 + reg;
                if (t < G-1) sH[row*WP + jcol] = f2bf(hv);
                else         out[(size_t)(b0 + row)*D + jcol] = hv;
            }
        }
        if (t < G-1) __syncthreads(); // RAW: h visible before next t's reads
    }
}

// ---------------- host ----------------

extern "C" void kernel_launch(void* const* d_in, const int* in_sizes, int n_in,
                              void* d_out, int out_size, void* d_ws, size_t ws_size,
                              hipStream_t stream) {
    const float* x   = (const float*)d_in[0];
    const int*   ei  = (const int*)  d_in[1];
    const float* W1l = (const float*)d_in[2];
    const float* W1r = (const float*)d_in[3];
    const float* b1  = (const float*)d_in[4];
    const float* W2l = (const float*)d_in[5];
    const float* W2r = (const float*)d_in[6];
    const float* b2  = (const float*)d_in[7];
    const float* Wih = (const float*)d_in[8];
    const float* Whh = (const float*)d_in[9];
    const float* bih = (const float*)d_in[10];
    const float* bhh = (const float*)d_in[11];
    float* out = (float*)d_out;

    char* ws = (char*)d_ws;
    size_t cur = 0;
    auto alloc = [&](size_t bytes)->void*{
        cur = (cur + 255) & ~(size_t)255;
        void* p = ws + cur; cur += bytes; return p;
    };
    int*   bkt  = (int*)alloc((size_t)SG*RGS*BCAP*4);   // buckets, then CSR in place
    int*   bcur = (int*)alloc((size_t)SG*RGS*4);
    int*   off2 = (int*)alloc((size_t)SG*NN*4);
    int*   deg2 = (int*)alloc((size_t)SG*NN*4);
    unsigned short* xb  = (unsigned short*)alloc((size_t)SG*NP*D*2);
    unsigned short* h1b = (unsigned short*)alloc((size_t)SG*NP*D*2);
    unsigned short* h2b = (unsigned short*)alloc((size_t)SG*NP*D*2);
    unsigned short* WL1 = (unsigned short*)alloc((size_t)G*64*128*2);
    unsigned short* WL2 = (unsigned short*)alloc((size_t)G*64*128*2);
    unsigned short* Wt  = (unsigned short*)alloc((size_t)256*128*2);
    float* bc   = (float*)alloc((size_t)256*4);
    (void)ws_size; (void)in_sizes; (void)n_in; (void)out_size;

    (void)hipMemsetAsync(bcur, 0, (size_t)SG*RGS*4, stream);

    convert_kernel<<<(SG*NN*16 + SG*3*16 + 255)/256, 256, 0, stream>>>(x, xb, h1b, h2b);
    binA_kernel  <<<dim3(CHUNKA, SG), 256, 0, stream>>>(ei, bcur, bkt);
    buildB_kernel<<<SG*RGS, 256, 0, stream>>>(bkt, bcur, off2, deg2);
    wprep2_kernel<<<321, 256, 0, stream>>>(W1l, W1r, W2l, W2r, Wih, Whh, bih, bhh,
                                           WL1, WL2, Wt, bc);

    layer_kernel<<<LTASKS, 256, 0, stream>>>(xb,  off2, deg2, bkt, WL1, b1, h1b);
    layer_kernel<<<LTASKS, 256, 0, stream>>>(h1b, off2, deg2, bkt, WL2, b2, h2b);

    lstm_kernel <<<(S*NN)/64, 256, 0, stream>>>(h2b, Wt, bc, out);
}